// Round 2
// baseline (458.929 us; speedup 1.0000x reference)
//
#include <hip/hip_runtime.h>
#include <hip/hip_bf16.h>

typedef __attribute__((ext_vector_type(8))) short bf16x8;
typedef __attribute__((ext_vector_type(8))) unsigned short u16x8;
typedef __attribute__((ext_vector_type(4))) float f32x4;

#define NB 4   // 4 x 16 = 64 kv columns per tile
#define MR 2   // 2 x 16 = 32 q rows per wave

__device__ __forceinline__ unsigned short f2bf(float f) {
    union { __hip_bfloat16 h; unsigned short u; } cv;
    cv.h = __float2bfloat16(f);
    return cv.u;
}

__global__ __launch_bounds__(256) void attn_fwd(
    const float* __restrict__ Vg, const float* __restrict__ Kg,
    const float* __restrict__ Qg, const int* __restrict__ Mg,
    float* __restrict__ Og)
{
    constexpr int S = 2048, H = 16, D = 64, SROW = H * D;
    // softmax scale 1/sqrt(1024) folded with log2(e): work in exp2 space
    constexpr float CST = 0.03125f * 1.44269504088896f;

    __shared__ unsigned short Klds[64 * 64];        // [kv][d]  bf16, XOR-swizzled
    __shared__ unsigned short VTlds[64 * 64];       // [d][kv]  bf16, XOR-swizzled
    __shared__ unsigned short Plds[4][32 * 64];     // per-wave [qr][kv]

    const int tid  = threadIdx.x;
    const int lane = tid & 63;
    const int w    = tid >> 6;
    const int c    = lane & 15;   // fragment col / A-row index
    const int g    = lane >> 4;   // fragment k-group

    const int bid = blockIdx.x;
    const int qb  = bid & 15;
    const int h   = (bid >> 4) & 15;
    const int b   = bid >> 8;

    const int q0 = qb * 128 + w * 32;

    const size_t base = ((size_t)b * S * H + h) * D;
    const float* Qp = Qg + base;
    const float* Kp = Kg + base;
    const float* Vp = Vg + base;
    float*       Op = Og + base;
    const int*   Mp = Mg + b * S;

    // ---- Q fragments, held in registers for all 32 KV tiles ----
    bf16x8 qf[MR][2];
#pragma unroll
    for (int mr = 0; mr < MR; ++mr) {
#pragma unroll
        for (int ks = 0; ks < 2; ++ks) {
            const float* qr = Qp + (size_t)(q0 + mr * 16 + c) * SROW + ks * 32 + g * 8;
            float4 x = *(const float4*)qr;
            float4 y = *(const float4*)(qr + 4);
            float v[8] = {x.x, x.y, x.z, x.w, y.x, y.y, y.z, y.w};
            bf16x8 f;
#pragma unroll
            for (int j = 0; j < 8; ++j) f[j] = (short)f2bf(v[j]);
            qf[mr][ks] = f;
        }
    }

    f32x4 oacc[MR][NB];
    float m_run[MR][4], l_run[MR][4];
#pragma unroll
    for (int mr = 0; mr < MR; ++mr) {
#pragma unroll
        for (int nb = 0; nb < NB; ++nb) oacc[mr][nb] = f32x4{0.f, 0.f, 0.f, 0.f};
#pragma unroll
        for (int r = 0; r < 4; ++r) { m_run[mr][r] = -INFINITY; l_run[mr][r] = 0.0f; }
    }

    const int kr  = tid >> 2;          // K-stage row 0..63
    const int kc0 = (tid & 3) << 4;    // K-stage col {0,16,32,48}
    const int vk  = (tid & 31) << 1;   // V-stage kv row pair base
    const int vd0 = (tid >> 5) << 3;   // V-stage d base {0..56}

    for (int t = 0; t < 32; ++t) {
        const int k0 = t * 64;

        // ---- stage K tile [64][64] -> Klds (fp32 -> bf16, swizzled b128 writes) ----
        {
            const float* src = Kp + (size_t)(k0 + kr) * SROW + kc0;
            float4 a0 = *(const float4*)(src);
            float4 a1 = *(const float4*)(src + 4);
            float4 a2 = *(const float4*)(src + 8);
            float4 a3 = *(const float4*)(src + 12);
            float v[16] = {a0.x,a0.y,a0.z,a0.w, a1.x,a1.y,a1.z,a1.w,
                           a2.x,a2.y,a2.z,a2.w, a3.x,a3.y,a3.z,a3.w};
            u16x8 w0, w1;
#pragma unroll
            for (int j = 0; j < 8; ++j) { w0[j] = f2bf(v[j]); w1[j] = f2bf(v[8 + j]); }
            char* kb = (char*)Klds + kr * 128;
            *(u16x8*)(kb + ((kc0 * 2)      ^ ((kr & 7) << 4))) = w0;
            *(u16x8*)(kb + ((kc0 * 2 + 16) ^ ((kr & 7) << 4))) = w1;
        }
        // ---- stage V tile transposed -> VTlds[d][kv] (conflict-free packed b32) ----
        {
            const float* s0 = Vp + (size_t)(k0 + vk) * SROW + vd0;
            const float* s1 = s0 + SROW;
            float4 a0 = *(const float4*)(s0);
            float4 a1 = *(const float4*)(s0 + 4);
            float4 b0 = *(const float4*)(s1);
            float4 b1 = *(const float4*)(s1 + 4);
            float va[8] = {a0.x,a0.y,a0.z,a0.w, a1.x,a1.y,a1.z,a1.w};
            float vb[8] = {b0.x,b0.y,b0.z,b0.w, b1.x,b1.y,b1.z,b1.w};
#pragma unroll
            for (int j = 0; j < 8; ++j) {
                int d = vd0 + j;
                unsigned int val = (unsigned int)f2bf(va[j]) |
                                   ((unsigned int)f2bf(vb[j]) << 16);
                *(unsigned int*)((char*)VTlds + d * 128 + ((vk * 2) ^ ((d & 7) << 4))) = val;
            }
        }
        __syncthreads();

        // ---- QK^T:  S = Q(16x32) . K^T  via mfma(qf, kf) ----
        f32x4 sacc[MR][NB];
#pragma unroll
        for (int mr = 0; mr < MR; ++mr)
#pragma unroll
            for (int nb = 0; nb < NB; ++nb) sacc[mr][nb] = f32x4{0.f, 0.f, 0.f, 0.f};

#pragma unroll
        for (int nb = 0; nb < NB; ++nb) {
#pragma unroll
            for (int ks = 0; ks < 2; ++ks) {
                bf16x8 kf = *(const bf16x8*)((char*)Klds + (nb * 16 + c) * 128 +
                                             ((ks * 64 + g * 16) ^ ((c & 7) << 4)));
#pragma unroll
                for (int mr = 0; mr < MR; ++mr)
                    sacc[mr][nb] = __builtin_amdgcn_mfma_f32_16x16x32_bf16(
                        qf[mr][ks], kf, sacc[mr][nb], 0, 0, 0);
            }
        }

        // ---- mask + scale into log2 space ----
        int mv[NB];
#pragma unroll
        for (int nb = 0; nb < NB; ++nb) mv[nb] = Mp[k0 + nb * 16 + c];
#pragma unroll
        for (int mr = 0; mr < MR; ++mr)
#pragma unroll
            for (int nb = 0; nb < NB; ++nb)
#pragma unroll
                for (int r = 0; r < 4; ++r)
                    sacc[mr][nb][r] = mv[nb] ? sacc[mr][nb][r] * CST : -1e20f;

        // ---- online softmax: row max, rescale factor ----
        float alpha[MR][4];
#pragma unroll
        for (int mr = 0; mr < MR; ++mr)
#pragma unroll
            for (int r = 0; r < 4; ++r) {
                float tmx = fmaxf(fmaxf(sacc[mr][0][r], sacc[mr][1][r]),
                                  fmaxf(sacc[mr][2][r], sacc[mr][3][r]));
#pragma unroll
                for (int off = 1; off < 16; off <<= 1)
                    tmx = fmaxf(tmx, __shfl_xor(tmx, off));
                float mn = fmaxf(m_run[mr][r], tmx);
                alpha[mr][r] = exp2f(m_run[mr][r] - mn);
                m_run[mr][r] = mn;
            }

        // p = exp2(lg - m)
#pragma unroll
        for (int mr = 0; mr < MR; ++mr)
#pragma unroll
            for (int nb = 0; nb < NB; ++nb)
#pragma unroll
                for (int r = 0; r < 4; ++r)
                    sacc[mr][nb][r] = exp2f(sacc[mr][nb][r] - m_run[mr][r]);

        // row sums + running denominator + O rescale
#pragma unroll
        for (int mr = 0; mr < MR; ++mr)
#pragma unroll
            for (int r = 0; r < 4; ++r) {
                float sm = sacc[mr][0][r] + sacc[mr][1][r] +
                           sacc[mr][2][r] + sacc[mr][3][r];
#pragma unroll
                for (int off = 1; off < 16; off <<= 1)
                    sm += __shfl_xor(sm, off);
                l_run[mr][r] = l_run[mr][r] * alpha[mr][r] + sm;
            }
#pragma unroll
        for (int mr = 0; mr < MR; ++mr)
#pragma unroll
            for (int nb = 0; nb < NB; ++nb)
#pragma unroll
                for (int r = 0; r < 4; ++r)
                    oacc[mr][nb][r] *= alpha[mr][r];

        // ---- write P (bf16) to per-wave LDS (C-layout -> A-layout repack) ----
        char* pb = (char*)Plds[w];
#pragma unroll
        for (int mr = 0; mr < MR; ++mr)
#pragma unroll
            for (int nb = 0; nb < NB; ++nb)
#pragma unroll
                for (int r = 0; r < 4; ++r) {
                    int row = mr * 16 + 4 * g + r;
                    int byo = (nb * 16 + c) * 2;
                    *(unsigned short*)(pb + row * 128 + (byo ^ ((row & 7) << 4))) =
                        f2bf(sacc[mr][nb][r]);
                }

        // ---- PV: O += P(16x32-per-step) . V ----
        bf16x8 pa[MR][2];
#pragma unroll
        for (int mr = 0; mr < MR; ++mr)
#pragma unroll
            for (int ks = 0; ks < 2; ++ks)
                pa[mr][ks] = *(const bf16x8*)(pb + (mr * 16 + c) * 128 +
                                              ((ks * 64 + g * 16) ^ ((c & 7) << 4)));
#pragma unroll
        for (int nd = 0; nd < NB; ++nd) {
#pragma unroll
            for (int ks = 0; ks < 2; ++ks) {
                bf16x8 vf = *(const bf16x8*)((char*)VTlds + (nd * 16 + c) * 128 +
                                             ((ks * 64 + g * 16) ^ ((c & 7) << 4)));
#pragma unroll
                for (int mr = 0; mr < MR; ++mr)
                    oacc[mr][nd] = __builtin_amdgcn_mfma_f32_16x16x32_bf16(
                        pa[mr][ks], vf, oacc[mr][nd], 0, 0, 0);
            }
        }
        __syncthreads();
    }

    // ---- epilogue: O / l, fp32 store ----
#pragma unroll
    for (int mr = 0; mr < MR; ++mr) {
        float rinv[4];
#pragma unroll
        for (int r = 0; r < 4; ++r) rinv[r] = 1.0f / l_run[mr][r];
#pragma unroll
        for (int nd = 0; nd < NB; ++nd)
#pragma unroll
            for (int r = 0; r < 4; ++r) {
                int qrow = q0 + mr * 16 + 4 * g + r;
                int dcol = nd * 16 + c;
                Op[(size_t)qrow * SROW + dcol] = oacc[mr][nd][r] * rinv[r];
            }
    }
}

extern "C" void kernel_launch(void* const* d_in, const int* in_sizes, int n_in,
                              void* d_out, int out_size, void* d_ws, size_t ws_size,
                              hipStream_t stream) {
    const float* V = (const float*)d_in[0];
    const float* K = (const float*)d_in[1];
    const float* Q = (const float*)d_in[2];
    const int*   M = (const int*)d_in[3];
    float*       O = (float*)d_out;
    // grid: 16 q-blocks x 16 heads x 4 batch = 1024 blocks, 256 threads
    attn_fwd<<<dim3(1024), dim3(256), 0, stream>>>(V, K, Q, M, O);
}

// Round 3
// 444.530 us; speedup vs baseline: 1.0324x; 1.0324x over previous
//
#include <hip/hip_runtime.h>
#include <hip/hip_bf16.h>

typedef __attribute__((ext_vector_type(8))) short bf16x8;
typedef __attribute__((ext_vector_type(8))) unsigned short u16x8;
typedef __attribute__((ext_vector_type(4))) float f32x4;

#define NB 4   // 4 x 16 = 64 kv columns per tile
#define MR 2   // 2 x 16 = 32 q rows per wave

__device__ __forceinline__ unsigned short f2bf(float f) {
    union { __hip_bfloat16 h; unsigned short u; } cv;
    cv.h = __float2bfloat16(f);
    return cv.u;
}

__global__ __launch_bounds__(256) void attn_fwd(
    const float* __restrict__ Vg, const float* __restrict__ Kg,
    const float* __restrict__ Qg, const int* __restrict__ Mg,
    float* __restrict__ Og)
{
    constexpr int S = 2048, H = 16, D = 64, SROW = H * D;
    // softmax scale 1/sqrt(1024) folded with log2(e): work in exp2 space
    constexpr float CST = 0.03125f * 1.44269504088896f;

    // double-buffered K/V tiles (T14 async-stage) + per-wave P scratch
    __shared__ unsigned short Klds[2][64 * 64];     // [kv][d]  bf16, XOR-swizzled
    __shared__ unsigned short VTlds[2][64 * 64];    // [d][kv]  bf16, XOR-swizzled
    __shared__ unsigned short Plds[4][32 * 64];     // per-wave [qr][kv]

    const int tid  = threadIdx.x;
    const int lane = tid & 63;
    const int w    = tid >> 6;
    const int c    = lane & 15;   // fragment col / A-row index
    const int g    = lane >> 4;   // fragment k-group

    const int bid = blockIdx.x;
    const int qb  = bid & 15;
    const int h   = (bid >> 4) & 15;
    const int b   = bid >> 8;

    const int q0 = qb * 128 + w * 32;

    const size_t base = ((size_t)b * S * H + h) * D;
    const float* Qp = Qg + base;
    const float* Kp = Kg + base;
    const float* Vp = Vg + base;
    float*       Op = Og + base;
    const int*   Mp = Mg + b * S;

    // staging coords
    const int kr  = tid >> 2;          // K-stage row 0..63
    const int kc0 = (tid & 3) << 4;    // K-stage col {0,16,32,48}
    const int vk  = (tid & 31) << 1;   // V-stage kv row pair base
    const int vd0 = (tid >> 5) << 3;   // V-stage d base {0..56}

    // ---- Q fragments, held in registers for all 32 KV tiles ----
    bf16x8 qf[MR][2];
#pragma unroll
    for (int mr = 0; mr < MR; ++mr) {
#pragma unroll
        for (int ks = 0; ks < 2; ++ks) {
            const float* qr = Qp + (size_t)(q0 + mr * 16 + c) * SROW + ks * 32 + g * 8;
            f32x4 x = *(const f32x4*)qr;
            f32x4 y = *(const f32x4*)(qr + 4);
            bf16x8 f;
#pragma unroll
            for (int j = 0; j < 4; ++j) { f[j] = (short)f2bf(x[j]); f[4 + j] = (short)f2bf(y[j]); }
            qf[mr][ks] = f;
        }
    }

    f32x4 oacc[MR][NB];
    float m_run[MR][4], l_run[MR][4];
#pragma unroll
    for (int mr = 0; mr < MR; ++mr) {
#pragma unroll
        for (int nb = 0; nb < NB; ++nb) oacc[mr][nb] = f32x4{0.f, 0.f, 0.f, 0.f};
#pragma unroll
        for (int r = 0; r < 4; ++r) { m_run[mr][r] = -INFINITY; l_run[mr][r] = 0.0f; }
    }

    // staging registers (live across compute — hides HBM latency under MFMA/softmax)
    f32x4 ks[4], vs[4];
    int   mnx[NB];

    auto STAGE_LOAD = [&](int t) {
        const int k0 = t * 64;
        const float* src = Kp + (size_t)(k0 + kr) * SROW + kc0;
        ks[0] = *(const f32x4*)(src);
        ks[1] = *(const f32x4*)(src + 4);
        ks[2] = *(const f32x4*)(src + 8);
        ks[3] = *(const f32x4*)(src + 12);
        const float* s0 = Vp + (size_t)(k0 + vk) * SROW + vd0;
        const float* s1 = s0 + SROW;
        vs[0] = *(const f32x4*)(s0);
        vs[1] = *(const f32x4*)(s0 + 4);
        vs[2] = *(const f32x4*)(s1);
        vs[3] = *(const f32x4*)(s1 + 4);
#pragma unroll
        for (int nb = 0; nb < NB; ++nb) mnx[nb] = Mp[k0 + nb * 16 + c];
    };

    auto STAGE_WRITE = [&](int buf) {
        // K tile: two swizzled b128 writes
        u16x8 w0, w1;
#pragma unroll
        for (int j = 0; j < 4; ++j) {
            w0[j]     = f2bf(ks[0][j]);
            w0[4 + j] = f2bf(ks[1][j]);
            w1[j]     = f2bf(ks[2][j]);
            w1[4 + j] = f2bf(ks[3][j]);
        }
        char* kb = (char*)Klds[buf] + kr * 128;
        *(u16x8*)(kb + ((kc0 * 2)      ^ ((kr & 7) << 4))) = w0;
        *(u16x8*)(kb + ((kc0 * 2 + 16) ^ ((kr & 7) << 4))) = w1;
        // V tile transposed: packed b32 writes
        char* vbase = (char*)VTlds[buf];
#pragma unroll
        for (int j = 0; j < 8; ++j) {
            int d = vd0 + j;
            float lo = (j < 4) ? vs[0][j] : vs[1][j - 4];
            float hi = (j < 4) ? vs[2][j] : vs[3][j - 4];
            unsigned int val = (unsigned int)f2bf(lo) | ((unsigned int)f2bf(hi) << 16);
            *(unsigned int*)(vbase + d * 128 + ((vk * 2) ^ ((d & 7) << 4))) = val;
        }
    };

    // ---- prologue: stage tile 0 into buffer 0 ----
    STAGE_LOAD(0);
    STAGE_WRITE(0);
    __syncthreads();

    for (int t = 0; t < 32; ++t) {
        const int cur = t & 1;
        const int nxt = cur ^ 1;

        // masks for the current tile (loaded during the previous iteration)
        int mv[NB];
#pragma unroll
        for (int nb = 0; nb < NB; ++nb) mv[nb] = mnx[nb];

        // issue next tile's global loads NOW; consume after compute (T14)
        if (t < 31) STAGE_LOAD(t + 1);

        // ---- QK^T:  S = Q(16x32) . K^T  via mfma(qf, kf) ----
        f32x4 sacc[MR][NB];
#pragma unroll
        for (int mr = 0; mr < MR; ++mr)
#pragma unroll
            for (int nb = 0; nb < NB; ++nb) sacc[mr][nb] = f32x4{0.f, 0.f, 0.f, 0.f};

        __builtin_amdgcn_s_setprio(1);
#pragma unroll
        for (int nb = 0; nb < NB; ++nb) {
#pragma unroll
            for (int ksl = 0; ksl < 2; ++ksl) {
                bf16x8 kf = *(const bf16x8*)((char*)Klds[cur] + (nb * 16 + c) * 128 +
                                             ((ksl * 64 + g * 16) ^ ((c & 7) << 4)));
#pragma unroll
                for (int mr = 0; mr < MR; ++mr)
                    sacc[mr][nb] = __builtin_amdgcn_mfma_f32_16x16x32_bf16(
                        qf[mr][ksl], kf, sacc[mr][nb], 0, 0, 0);
            }
        }
        __builtin_amdgcn_s_setprio(0);

        // ---- mask + scale into log2 space ----
#pragma unroll
        for (int mr = 0; mr < MR; ++mr)
#pragma unroll
            for (int nb = 0; nb < NB; ++nb)
#pragma unroll
                for (int r = 0; r < 4; ++r)
                    sacc[mr][nb][r] = mv[nb] ? sacc[mr][nb][r] * CST : -1e20f;

        // ---- online softmax: row max, rescale factor ----
        float alpha[MR][4];
#pragma unroll
        for (int mr = 0; mr < MR; ++mr)
#pragma unroll
            for (int r = 0; r < 4; ++r) {
                float tmx = fmaxf(fmaxf(sacc[mr][0][r], sacc[mr][1][r]),
                                  fmaxf(sacc[mr][2][r], sacc[mr][3][r]));
#pragma unroll
                for (int off = 1; off < 16; off <<= 1)
                    tmx = fmaxf(tmx, __shfl_xor(tmx, off));
                float mn = fmaxf(m_run[mr][r], tmx);
                alpha[mr][r] = exp2f(m_run[mr][r] - mn);
                m_run[mr][r] = mn;
            }

        // p = exp2(lg - m)
#pragma unroll
        for (int mr = 0; mr < MR; ++mr)
#pragma unroll
            for (int nb = 0; nb < NB; ++nb)
#pragma unroll
                for (int r = 0; r < 4; ++r)
                    sacc[mr][nb][r] = exp2f(sacc[mr][nb][r] - m_run[mr][r]);

        // row sums + running denominator + O rescale
#pragma unroll
        for (int mr = 0; mr < MR; ++mr)
#pragma unroll
            for (int r = 0; r < 4; ++r) {
                float sm = sacc[mr][0][r] + sacc[mr][1][r] +
                           sacc[mr][2][r] + sacc[mr][3][r];
#pragma unroll
                for (int off = 1; off < 16; off <<= 1)
                    sm += __shfl_xor(sm, off);
                l_run[mr][r] = l_run[mr][r] * alpha[mr][r] + sm;
            }
#pragma unroll
        for (int mr = 0; mr < MR; ++mr)
#pragma unroll
            for (int nb = 0; nb < NB; ++nb)
#pragma unroll
                for (int r = 0; r < 4; ++r)
                    oacc[mr][nb][r] *= alpha[mr][r];

        // ---- write P (bf16) to per-wave LDS (C-layout -> A-layout repack) ----
        char* pb = (char*)Plds[w];
#pragma unroll
        for (int mr = 0; mr < MR; ++mr)
#pragma unroll
            for (int nb = 0; nb < NB; ++nb)
#pragma unroll
                for (int r = 0; r < 4; ++r) {
                    int row = mr * 16 + 4 * g + r;
                    int byo = (nb * 16 + c) * 2;
                    *(unsigned short*)(pb + row * 128 + (byo ^ ((row & 7) << 4))) =
                        f2bf(sacc[mr][nb][r]);
                }

        // ---- PV: O += P(16x32-per-step) . V ----
        bf16x8 pa[MR][2];
#pragma unroll
        for (int mr = 0; mr < MR; ++mr)
#pragma unroll
            for (int ksl = 0; ksl < 2; ++ksl)
                pa[mr][ksl] = *(const bf16x8*)(pb + (mr * 16 + c) * 128 +
                                               ((ksl * 64 + g * 16) ^ ((c & 7) << 4)));
        __builtin_amdgcn_s_setprio(1);
#pragma unroll
        for (int nd = 0; nd < NB; ++nd) {
#pragma unroll
            for (int ksl = 0; ksl < 2; ++ksl) {
                bf16x8 vf = *(const bf16x8*)((char*)VTlds[cur] + (nd * 16 + c) * 128 +
                                             ((ksl * 64 + g * 16) ^ ((c & 7) << 4)));
#pragma unroll
                for (int mr = 0; mr < MR; ++mr)
                    oacc[mr][nd] = __builtin_amdgcn_mfma_f32_16x16x32_bf16(
                        pa[mr][ksl], vf, oacc[mr][nd], 0, 0, 0);
            }
        }
        __builtin_amdgcn_s_setprio(0);

        // ---- write next tile's staged data to the other buffer, then one barrier ----
        if (t < 31) STAGE_WRITE(nxt);
        __syncthreads();
    }

    // ---- epilogue: O / l, fp32 store ----
#pragma unroll
    for (int mr = 0; mr < MR; ++mr) {
        float rinv[4];
#pragma unroll
        for (int r = 0; r < 4; ++r) rinv[r] = 1.0f / l_run[mr][r];
#pragma unroll
        for (int nd = 0; nd < NB; ++nd)
#pragma unroll
            for (int r = 0; r < 4; ++r) {
                int qrow = q0 + mr * 16 + 4 * g + r;
                int dcol = nd * 16 + c;
                Op[(size_t)qrow * SROW + dcol] = oacc[mr][nd][r] * rinv[r];
            }
    }
}

extern "C" void kernel_launch(void* const* d_in, const int* in_sizes, int n_in,
                              void* d_out, int out_size, void* d_ws, size_t ws_size,
                              hipStream_t stream) {
    const float* V = (const float*)d_in[0];
    const float* K = (const float*)d_in[1];
    const float* Q = (const float*)d_in[2];
    const int*   M = (const int*)d_in[3];
    float*       O = (float*)d_out;
    // grid: 16 q-blocks x 16 heads x 4 batch = 1024 blocks, 256 threads
    attn_fwd<<<dim3(1024), dim3(256), 0, stream>>>(V, K, Q, M, O);
}

// Round 4
// 312.106 us; speedup vs baseline: 1.4704x; 1.4243x over previous
//
#include <hip/hip_runtime.h>
#include <hip/hip_bf16.h>

typedef __attribute__((ext_vector_type(8))) short bf16x8;
typedef __attribute__((ext_vector_type(8))) unsigned short u16x8;
typedef __attribute__((ext_vector_type(4))) float f32x4;

#define NB 4   // 4 x 16 = 64 kv columns per tile

__device__ __forceinline__ unsigned short f2bf(float f) {
    union { __hip_bfloat16 h; unsigned short u; } cv;
    cv.h = __float2bfloat16(f);
    return cv.u;
}

__global__ __launch_bounds__(256, 4) void attn_fwd(
    const float* __restrict__ Vg, const float* __restrict__ Kg,
    const float* __restrict__ Qg, const int* __restrict__ Mg,
    float* __restrict__ Og)
{
    constexpr int S = 2048, H = 16, D = 64, SROW = H * D;
    // softmax scale 1/sqrt(1024) folded with log2(e): work in exp2 space
    constexpr float CST = 0.03125f * 1.44269504088896f;

    // double-buffered K/V tiles + per-wave P scratch: 16+16+8 = 40 KB -> 4 blocks/CU
    __shared__ unsigned short Klds[2][64 * 64];     // [kv][d]  bf16, XOR-swizzled
    __shared__ unsigned short VTlds[2][64 * 64];    // [d][kv]  bf16, XOR-swizzled
    __shared__ unsigned short Plds[4][16 * 64];     // per-wave [qr][kv]

    const int tid  = threadIdx.x;
    const int lane = tid & 63;
    const int w    = tid >> 6;
    const int c    = lane & 15;   // fragment col index
    const int g    = lane >> 4;   // fragment k-group

    // T1: bijective XCD swizzle (2048 blocks, 8 XCDs, 256 per XCD)
    // -> each XCD covers 8 contiguous (b,h) K/V panels for L2 locality
    const int logical = (blockIdx.x & 7) * 256 + (blockIdx.x >> 3);
    const int qb  = logical & 31;
    const int h   = (logical >> 5) & 15;
    const int b   = logical >> 9;

    const int q0 = qb * 64 + w * 16;   // 16 q-rows per wave (MR=1)

    const size_t base = ((size_t)b * S * H + h) * D;
    const float* Qp = Qg + base;
    const float* Kp = Kg + base;
    const float* Vp = Vg + base;
    float*       Op = Og + base;
    const int*   Mp = Mg + b * S;

    // staging coords
    const int kr  = tid >> 2;          // K-stage row 0..63
    const int kc0 = (tid & 3) << 4;    // K-stage col {0,16,32,48}
    const int vk  = (tid & 31) << 1;   // V-stage kv row pair base
    const int vd0 = (tid >> 5) << 3;   // V-stage d base {0..56}

    // ---- Q fragments, held in registers for all 32 KV tiles ----
    bf16x8 qf[2];
#pragma unroll
    for (int ks = 0; ks < 2; ++ks) {
        const float* qr = Qp + (size_t)(q0 + c) * SROW + ks * 32 + g * 8;
        f32x4 x = *(const f32x4*)qr;
        f32x4 y = *(const f32x4*)(qr + 4);
        bf16x8 f;
#pragma unroll
        for (int j = 0; j < 4; ++j) { f[j] = (short)f2bf(x[j]); f[4 + j] = (short)f2bf(y[j]); }
        qf[ks] = f;
    }

    f32x4 oacc[NB];
    float m_run[4], l_run[4];
#pragma unroll
    for (int nb = 0; nb < NB; ++nb) oacc[nb] = f32x4{0.f, 0.f, 0.f, 0.f};
#pragma unroll
    for (int r = 0; r < 4; ++r) { m_run[r] = -INFINITY; l_run[r] = 0.0f; }

    // staging registers (live across compute — hides HBM latency under MFMA/softmax)
    f32x4 kstg[4], vstg[4];
    int   mnx[NB];

    auto STAGE_LOAD = [&](int t) {
        const int k0 = t * 64;
        const float* src = Kp + (size_t)(k0 + kr) * SROW + kc0;
        kstg[0] = *(const f32x4*)(src);
        kstg[1] = *(const f32x4*)(src + 4);
        kstg[2] = *(const f32x4*)(src + 8);
        kstg[3] = *(const f32x4*)(src + 12);
        const float* s0 = Vp + (size_t)(k0 + vk) * SROW + vd0;
        const float* s1 = s0 + SROW;
        vstg[0] = *(const f32x4*)(s0);
        vstg[1] = *(const f32x4*)(s0 + 4);
        vstg[2] = *(const f32x4*)(s1);
        vstg[3] = *(const f32x4*)(s1 + 4);
#pragma unroll
        for (int nb = 0; nb < NB; ++nb) mnx[nb] = Mp[k0 + nb * 16 + c];
    };

    auto STAGE_WRITE = [&](int buf) {
        // K tile: two swizzled b128 writes
        u16x8 w0, w1;
#pragma unroll
        for (int j = 0; j < 4; ++j) {
            w0[j]     = f2bf(kstg[0][j]);
            w0[4 + j] = f2bf(kstg[1][j]);
            w1[j]     = f2bf(kstg[2][j]);
            w1[4 + j] = f2bf(kstg[3][j]);
        }
        char* kb = (char*)Klds[buf] + kr * 128;
        *(u16x8*)(kb + ((kc0 * 2)      ^ ((kr & 7) << 4))) = w0;
        *(u16x8*)(kb + ((kc0 * 2 + 16) ^ ((kr & 7) << 4))) = w1;
        // V tile transposed: packed b32 writes
        char* vbase = (char*)VTlds[buf];
#pragma unroll
        for (int j = 0; j < 8; ++j) {
            int d = vd0 + j;
            float lo = (j < 4) ? vstg[0][j] : vstg[1][j - 4];
            float hi = (j < 4) ? vstg[2][j] : vstg[3][j - 4];
            unsigned int val = (unsigned int)f2bf(lo) | ((unsigned int)f2bf(hi) << 16);
            *(unsigned int*)(vbase + d * 128 + ((vk * 2) ^ ((d & 7) << 4))) = val;
        }
    };

    // ---- prologue: stage tile 0 into buffer 0 ----
    STAGE_LOAD(0);
    STAGE_WRITE(0);
    __syncthreads();

    for (int t = 0; t < 32; ++t) {
        const int cur = t & 1;
        const int nxt = cur ^ 1;

        // masks for the current tile (loaded during the previous iteration)
        int mv[NB];
#pragma unroll
        for (int nb = 0; nb < NB; ++nb) mv[nb] = mnx[nb];

        // issue next tile's global loads NOW; consume after compute (T14)
        if (t < 31) STAGE_LOAD(t + 1);

        // ---- QK^T:  S = Q(16x64-tile) . K^T  via mfma(qf, kf) ----
        f32x4 sacc[NB];
#pragma unroll
        for (int nb = 0; nb < NB; ++nb) sacc[nb] = f32x4{0.f, 0.f, 0.f, 0.f};

        __builtin_amdgcn_s_setprio(1);
#pragma unroll
        for (int nb = 0; nb < NB; ++nb) {
#pragma unroll
            for (int ksl = 0; ksl < 2; ++ksl) {
                bf16x8 kf = *(const bf16x8*)((char*)Klds[cur] + (nb * 16 + c) * 128 +
                                             ((ksl * 64 + g * 16) ^ ((c & 7) << 4)));
                sacc[nb] = __builtin_amdgcn_mfma_f32_16x16x32_bf16(
                    qf[ksl], kf, sacc[nb], 0, 0, 0);
            }
        }
        __builtin_amdgcn_s_setprio(0);

        // ---- mask + scale into log2 space ----
#pragma unroll
        for (int nb = 0; nb < NB; ++nb)
#pragma unroll
            for (int r = 0; r < 4; ++r)
                sacc[nb][r] = mv[nb] ? sacc[nb][r] * CST : -1e20f;

        // ---- online softmax: row max, rescale factor ----
        float alpha[4];
#pragma unroll
        for (int r = 0; r < 4; ++r) {
            float tmx = fmaxf(fmaxf(sacc[0][r], sacc[1][r]),
                              fmaxf(sacc[2][r], sacc[3][r]));
#pragma unroll
            for (int off = 1; off < 16; off <<= 1)
                tmx = fmaxf(tmx, __shfl_xor(tmx, off));
            float mn = fmaxf(m_run[r], tmx);
            alpha[r] = __builtin_amdgcn_exp2f(m_run[r] - mn);
            m_run[r] = mn;
        }

        // p = exp2(lg - m)
#pragma unroll
        for (int nb = 0; nb < NB; ++nb)
#pragma unroll
            for (int r = 0; r < 4; ++r)
                sacc[nb][r] = __builtin_amdgcn_exp2f(sacc[nb][r] - m_run[r]);

        // row sums + running denominator + O rescale
#pragma unroll
        for (int r = 0; r < 4; ++r) {
            float sm = sacc[0][r] + sacc[1][r] + sacc[2][r] + sacc[3][r];
#pragma unroll
            for (int off = 1; off < 16; off <<= 1)
                sm += __shfl_xor(sm, off);
            l_run[r] = l_run[r] * alpha[r] + sm;
        }
#pragma unroll
        for (int nb = 0; nb < NB; ++nb)
#pragma unroll
            for (int r = 0; r < 4; ++r)
                oacc[nb][r] *= alpha[r];

        // ---- write P (bf16) to per-wave LDS (C-layout -> A-layout repack) ----
        char* pb = (char*)Plds[w];
#pragma unroll
        for (int nb = 0; nb < NB; ++nb)
#pragma unroll
            for (int r = 0; r < 4; ++r) {
                int row = 4 * g + r;
                int byo = (nb * 16 + c) * 2;
                *(unsigned short*)(pb + row * 128 + (byo ^ ((row & 7) << 4))) =
                    f2bf(sacc[nb][r]);
            }

        // ---- PV: O += P(16x64) . V ----
        bf16x8 pa[2];
#pragma unroll
        for (int ksl = 0; ksl < 2; ++ksl)
            pa[ksl] = *(const bf16x8*)(pb + c * 128 +
                                       ((ksl * 64 + g * 16) ^ ((c & 7) << 4)));
        __builtin_amdgcn_s_setprio(1);
#pragma unroll
        for (int nd = 0; nd < NB; ++nd) {
#pragma unroll
            for (int ksl = 0; ksl < 2; ++ksl) {
                bf16x8 vf = *(const bf16x8*)((char*)VTlds[cur] + (nd * 16 + c) * 128 +
                                             ((ksl * 64 + g * 16) ^ ((c & 7) << 4)));
                oacc[nd] = __builtin_amdgcn_mfma_f32_16x16x32_bf16(
                    pa[ksl], vf, oacc[nd], 0, 0, 0);
            }
        }
        __builtin_amdgcn_s_setprio(0);

        // ---- write next tile's staged data to the other buffer, then one barrier ----
        if (t < 31) STAGE_WRITE(nxt);
        __syncthreads();
    }

    // ---- epilogue: O / l, fp32 store ----
    float rinv[4];
#pragma unroll
    for (int r = 0; r < 4; ++r) rinv[r] = 1.0f / l_run[r];
#pragma unroll
    for (int nd = 0; nd < NB; ++nd)
#pragma unroll
        for (int r = 0; r < 4; ++r) {
            int qrow = q0 + 4 * g + r;
            int dcol = nd * 16 + c;
            Op[(size_t)qrow * SROW + dcol] = oacc[nd][r] * rinv[r];
        }
}

extern "C" void kernel_launch(void* const* d_in, const int* in_sizes, int n_in,
                              void* d_out, int out_size, void* d_ws, size_t ws_size,
                              hipStream_t stream) {
    const float* V = (const float*)d_in[0];
    const float* K = (const float*)d_in[1];
    const float* Q = (const float*)d_in[2];
    const int*   M = (const int*)d_in[3];
    float*       O = (float*)d_out;
    // grid: 32 q-blocks x 16 heads x 4 batch = 2048 blocks, 256 threads
    attn_fwd<<<dim3(2048), dim3(256), 0, stream>>>(V, K, Q, M, O);
}